// Round 5
// baseline (307.465 us; speedup 1.0000x reference)
//
#include <hip/hip_runtime.h>
#include <hip/hip_fp16.h>

#define NN 2048
#define ITERS 1000
#define NBLK 256
#define RPW 8  // rows (and cols) per workgroup
#define EPS 3e-3f

typedef __attribute__((ext_vector_type(4))) float floatx4;
typedef unsigned long long u64;

#define AGENT __HIP_MEMORY_SCOPE_AGENT
#define WG __HIP_MEMORY_SCOPE_WORKGROUP

// s_waitcnt simm16 encodings (gfx9): vmcnt[3:0]@[3:0], vmcnt[5:4]@[15:14],
// expcnt@[6:4], lgkmcnt@[11:8]
#define WC_VM6   0x0F76  // vmcnt(6)  lgkm(15) exp(7)
#define WC_VM0   0x0F70  // vmcnt(0)  lgkm(15) exp(7)

static __device__ __forceinline__ void agstore64(u64* p, u64 v) {
  __hip_atomic_store(p, v, __ATOMIC_RELAXED, AGENT);
}
static __device__ __forceinline__ u64 agload64(const u64* p) {
  return __hip_atomic_load(p, __ATOMIC_RELAXED, AGENT);
}

// R17: f16x4 PACKED exchange. One u64 carries FOUR f16 values (rows 4W..4W+3
// for word index W); the low 2 mantissa bits of value0 hold the generation
// tag. 2048 values -> 512 words; each thread polls 2 words. Halves both MALL
// byte traffic and the per-sweep poll cost vs R16's f32 pairs. Numerics:
// u,v in ~[1e-3,1] (f16-safe range); rel err 4.9e-4 (2e-3 for the one
// tag-stolen value) << fp8 output quantization (6%). Quantization is
// deterministic, so converged values repeat bit-identically and the
// convergence residual still reaches 0.
// Tag safety (unchanged from R16): skew <= 1 generation; tag2=(tag+1)&3
// alternates 3/1 for u, 0/2 for v. Poison 0xAA.. has low2=2; first v-gen
// with tag2=2 is tag 5, polled only after a full tag-3 gather proved every
// recV word was written. u polls (3/1) never match poison.
static __device__ __forceinline__ unsigned tagbits(unsigned tag) {
  return (tag + 1) & 3u;
}
static __device__ __forceinline__ unsigned short f16b(float x) {
  return __half_as_ushort(__float2half(x));
}
static __device__ __forceinline__ float f16f(unsigned short b) {
  return __half2float(__ushort_as_half(b));
}
static __device__ __forceinline__ u64 pack4(float a, float b, float c, float d,
                                            unsigned t2) {
  return ((u64)f16b(d) << 48) | ((u64)f16b(c) << 32) | ((u64)f16b(b) << 16) |
         (u64)((f16b(a) & 0xFFFCu) | t2);
}

static __device__ __forceinline__ void poll2(const u64* rec, int tid,
                                             unsigned t2, float* x) {
  const u64* base = rec + tid * 2;
  unsigned got = 0;
  while (got != 0x3u) {
#pragma unroll
    for (int j = 0; j < 2; j++)
      if (!(got & (1u << j))) {
        u64 wv = agload64(base + j);
        if (((unsigned)wv & 3u) == t2) {
          x[4 * j + 0] = f16f((unsigned short)(wv & 0xFFFCu));
          x[4 * j + 1] = f16f((unsigned short)(wv >> 16));
          x[4 * j + 2] = f16f((unsigned short)(wv >> 32));
          x[4 * j + 3] = f16f((unsigned short)(wv >> 48));
          got |= 1u << j;
        }
      }
  }
}

static __device__ __forceinline__ void gather64(const u64* rec, int tid,
                                                float* vec, unsigned tag) {
  float x[8];
  poll2(rec, tid, tagbits(tag), x);
#pragma unroll
  for (int j = 0; j < 8; j++) vec[tid * 8 + j] = x[j];
  __syncthreads();
}

static __device__ __forceinline__ bool gather64_check(const u64* rec, int tid,
                                                      float* vec, unsigned tag,
                                                      float* pv) {
  float x[8];
  poll2(rec, tid, tagbits(tag), x);
  float resid = 0.f;
#pragma unroll
  for (int j = 0; j < 8; j++) {
    resid = fmaxf(resid, fabsf(x[j] / pv[j] - 1.0f));
    pv[j] = x[j];
    vec[tid * 8 + j] = x[j];
  }
  return __syncthreads_and(resid < EPS) != 0;
}

// Pair-group publish: waves (2q, 2q+1) share word 2g+q (rows 8g+4q..+3).
// Odd wave hands its two values to the even wave via LDS (release flag =
// exchange tag, strictly increasing -> no reset needed); even wave packs
// 4xf16 and issues the single MALL store. No added MALL round-trips.
// No deadlock: odd's next gather needs even's store; even's spin needs
// odd's flag, which odd sets unconditionally before gathering.
static __device__ __forceinline__ void publish_pair(u64* rec, int g, int w,
                                                    int lane, float va,
                                                    float vb, float* hand,
                                                    unsigned* handflag,
                                                    unsigned tag) {
  if (lane == 0) {
    int q = w >> 1, r0 = 2 * w;
    if (w & 1) {
      hand[r0] = va;
      hand[r0 + 1] = vb;
      __hip_atomic_store(&handflag[q], tag, __ATOMIC_RELEASE, WG);
    } else {
      while (__hip_atomic_load(&handflag[q], __ATOMIC_ACQUIRE, WG) != tag) {}
      agstore64(&rec[2 * g + q],
                pack4(va, vb, hand[r0 + 2], hand[r0 + 3], tagbits(tag)));
    }
  }
}

__global__ __launch_bounds__(256) void sinkhorn_kernel(
    const float* __restrict__ M, u64* recU, u64* recV,
    unsigned char* __restrict__ Pb, unsigned char* __restrict__ Wb)
{
  __shared__ float rowsA[RPW][NN];   // 64 KB: exp(100*M) rows (wave-local)
  __shared__ float colsA[RPW][NN];   // 64 KB: exp(100*M) cols (transposed)
  __shared__ float vec[NN];          // 8 KB: gathered u or v
  __shared__ float myu[RPW];
  __shared__ float hand[RPW];        // odd->even wave value hand-off
  __shared__ unsigned handflag[2];   // per pair-group generation flag

  const int g = blockIdx.x;
  const int tid = threadIdx.x;
  const int w = tid >> 6;
  const int lane = tid & 63;
  const int r0 = 2 * w, r1 = r0 + 1;

  // Row slab load with FUSED exp (no rowmax shift needed: a left-diagonal
  // factor is absorbed by u at the first row normalization; M in
  // (-0.0221,0.0221) -> exp(100M) in (0.11,9.2), no overflow). R11-verified.
  {
    const float4* src = (const float4*)(M + (size_t)g * RPW * NN);
    float4* dst = (float4*)&rowsA[0][0];
    for (int c = tid; c < RPW * NN / 4; c += 256) {
      float4 x = src[c];
      x.x = __expf(100.0f * x.x);
      x.y = __expf(100.0f * x.y);
      x.z = __expf(100.0f * x.z);
      x.w = __expf(100.0f * x.w);
      dst[c] = x;
    }
  }
  if (tid < 2) handflag[tid] = 0;  // covered by the syncthreads below

  // column strip loads into registers (overlap everything)
  float4 sx0[8], sx1[8];
#pragma unroll
  for (int rr = 0; rr < 8; rr++) {
    const float* src = M + (size_t)(tid * 8 + rr) * NN + RPW * g;
    sx0[rr] = *(const float4*)src;
    sx1[rr] = *(const float4*)(src + 4);
  }

  __syncthreads();  // rowsA ready; rows wave-local after this

  // v=1 row sums (wave-local), publish u tag 2
  float s0 = 0.f, s1 = 0.f;
#pragma unroll 8
  for (int k = lane; k < NN; k += 64) {
    s0 += rowsA[r0][k];
    s1 += rowsA[r1][k];
  }
  for (int off = 32; off; off >>= 1) {
    s0 += __shfl_xor(s0, off, 64);
    s1 += __shfl_xor(s1, off, 64);
  }
  {
    float u0 = 1.0f / s0, u1 = 1.0f / s1;
    if (lane == 0) {
      myu[r0] = u0;
      myu[r1] = u1;
    }
    publish_pair(recU, g, w, lane, u0, u1, hand, handflag, 2);
  }

  // colsA = exp(100*strip), off the critical path
#pragma unroll
  for (int rr = 0; rr < 8; rr++) {
    int i = tid * 8 + rr;
    colsA[0][i] = __expf(100.0f * sx0[rr].x);
    colsA[1][i] = __expf(100.0f * sx0[rr].y);
    colsA[2][i] = __expf(100.0f * sx0[rr].z);
    colsA[3][i] = __expf(100.0f * sx0[rr].w);
    colsA[4][i] = __expf(100.0f * sx1[rr].x);
    colsA[5][i] = __expf(100.0f * sx1[rr].y);
    colsA[6][i] = __expf(100.0f * sx1[rr].z);
    colsA[7][i] = __expf(100.0f * sx1[rr].w);
  }

  // it=0 col pass
  float pv[8];
#pragma unroll
  for (int j = 0; j < 8; j++) pv[j] = 1.0f;

  gather64(recU, tid, vec, 2);  // barrier also covers colsA writes
  {
    float t0 = 0.f, t1 = 0.f;
#pragma unroll 8
    for (int k = lane; k < NN; k += 64) {
      float uu = vec[k];
      t0 += colsA[r0][k] * uu;
      t1 += colsA[r1][k] * uu;
    }
    for (int off = 32; off; off >>= 1) {
      t0 += __shfl_xor(t0, off, 64);
      t1 += __shfl_xor(t1, off, 64);
    }
    publish_pair(recV, g, w, lane, 1.0f / t0, 1.0f / t1, hand, handflag, 3);
  }

  // main loop: u tags 2+2it, v tags 3+2it
  bool done = false;
  unsigned utag = 4;
  for (int it = 1; it < ITERS; it++, utag += 2) {
    if (gather64_check(recV, tid, vec, utag - 1, pv)) { done = true; break; }
    float a0 = 0.f, a1 = 0.f;
#pragma unroll 8
    for (int k = lane; k < NN; k += 64) {
      float vv = vec[k];
      a0 += rowsA[r0][k] * vv;
      a1 += rowsA[r1][k] * vv;
    }
    for (int off = 32; off; off >>= 1) {
      a0 += __shfl_xor(a0, off, 64);
      a1 += __shfl_xor(a1, off, 64);
    }
    {
      float u0 = 1.0f / a0, u1 = 1.0f / a1;
      if (lane == 0) {
        myu[r0] = u0;
        myu[r1] = u1;
      }
      publish_pair(recU, g, w, lane, u0, u1, hand, handflag, utag);
    }

    gather64(recU, tid, vec, utag);
    float t0 = 0.f, t1 = 0.f;
#pragma unroll 8
    for (int k = lane; k < NN; k += 64) {
      float uu = vec[k];
      t0 += colsA[r0][k] * uu;
      t1 += colsA[r1][k] * uu;
    }
    for (int off = 32; off; off >>= 1) {
      t0 += __shfl_xor(t0, off, 64);
      t1 += __shfl_xor(t1, off, 64);
    }
    publish_pair(recV, g, w, lane, 1.0f / t0, 1.0f / t1, hand, handflag,
                 utag + 1);
  }
  if (!done) gather64(recV, tid, vec, 2 * ITERS + 1);

  // epilogue: P = 256*diag(u) m0 diag(v) (e4m3), W = row suffix sums (e4m3)
  for (int idx = tid; idx < RPW * NN / 2; idx += 256) {
    int r = idx >> 10, j2 = (idx & 1023) * 2;
    float p0 = 256.0f * myu[r] * rowsA[r][j2] * vec[j2];
    float p1 = 256.0f * myu[r] * rowsA[r][j2 + 1] * vec[j2 + 1];
    int pk = __builtin_amdgcn_cvt_pk_fp8_f32(p0, p1, 0, false);
    ((unsigned short*)Pb)[((((size_t)(RPW * g + r)) << 11) | j2) >> 1] = (unsigned short)pk;
  }
  for (int rr = 0; rr < 2; rr++) {
    int r = 2 * w + rr;
    float ur = myu[r];
    int base = lane * 32;
    float cs = 0.f;
    for (int t = 0; t < 32; t++) {
      int k = base + ((t + lane) & 31);  // rotated: dodge bank conflicts
      cs += ur * rowsA[r][k] * vec[k];
    }
    float s = cs;
    for (int off = 1; off < 64; off <<= 1) {
      float t = __shfl_down(s, off, 64);
      if (lane + off < 64) s += t;
    }
    float run = __shfl_down(s, 1, 64);  // sum of later chunks
    if (lane == 63) run = 0.f;
    float wv[32];
#pragma unroll
    for (int k = 31; k >= 0; k--) {
      int kk = base + k;
      run += ur * rowsA[r][kk] * vec[kk];
      wv[k] = run;
    }
#pragma unroll
    for (int pq = 0; pq < 16; pq++) {
      int pk = __builtin_amdgcn_cvt_pk_fp8_f32(wv[2 * pq], wv[2 * pq + 1], 0, false);
      ((unsigned short*)Wb)[((((size_t)(RPW * g + r)) << 11) | (base + 2 * pq)) >> 1] =
          (unsigned short)pk;
    }
  }
}

// out[i][j] = (1/256) * sum_a P[i][a] * W[j][a]  (NT GEMM, e4m3 in, fp32 out)
//
// R17: TWO SLABS PER BARRIER. Per-slab sync (barrier + vmcnt wait) bought
// only 16 MFMAs/wave; pair slabs -> 16 iterations, each:
//   wait vmcnt(6) [slabs 2i,2i+1 landed; 2 slabs x 3 loads stay in flight]
//   barrier; issue slabs 2i+4,2i+5; consume slabs 2i,2i+1.
// Ring-6 safety: iter-i issue targets bufs (2i+4)%6,(2i+5)%6 = the pair
// consumed at iter i-1; any wave past barrier i already retired those
// ds_reads (lgkmcnt forced before its MFMAs). In-flight never 0 until the
// final iteration (T4). Barriers 28 -> 16, MFMA-per-sync x2. Tiling
// unchanged (64x128, grid 512 = 2 blocks/CU, 72 KB LDS); XOR-granule
// swizzle and XCD pinning (blk%8 = by%8) bit-identical.
// R18: final iteration PEELED (s_waitcnt arg must be a literal constant).
__global__ __launch_bounds__(256, 2) void gemm_nt_fp8(const unsigned char* __restrict__ P,
                                                      const unsigned char* __restrict__ W,
                                                      float* __restrict__ out)
{
  __shared__ unsigned char SA[6][12288];  // 72 KB
  const int tid = threadIdx.x;
  const int w = tid >> 6, lane = tid & 63;
  const int quad = lane >> 4, l16 = lane & 15;
  const int by = blockIdx.x & 15;   // W-strip id -> pins XCD (blk%8 = by%8)
  const int bx = blockIdx.x >> 4;   // P-strip id (0..31)
  const int i0 = bx * 64, j0 = by * 128;
  const int wc = w * 32;            // wave N base within tile

  const int lrow = lane >> 2;        // staging row within 16-row chunk
  const int lp2 = (lane & 3) * 2;    // staging granule pair base

  floatx4 acc[4][2] = {};

  // issue one 64-wide K-slab into buffer b: 12 chunks of 1 KB, 3 per wave.
  // rows 0..63 = P tile rows, rows 64..191 = W tile rows.
  auto issue = [&](int k0, int b) {
#pragma unroll
    for (int c = 0; c < 3; c++) {
      int q = w * 3 + c;           // wave-uniform chunk id 0..11
      int r = q * 16 + lrow;       // combined row 0..191
      const unsigned char* gsrc =
          (q < 4 ? P + (size_t)(i0 + r) * NN
                 : W + (size_t)(j0 + r - 64) * NN) +
          k0 + ((lp2 ^ (r & 6)) * 8);
      __builtin_amdgcn_global_load_lds(
          (const __attribute__((address_space(1))) void*)gsrc,
          (__attribute__((address_space(3))) void*)(&SA[b][q * 1024]), 16, 0, 0);
    }
  };

  // consume one slab from buffer b
  auto consume = [&](int b) {
#pragma unroll
    for (int kc = 0; kc < 2; kc++) {
      long a[4], b2[2];
      int cg = kc * 4 + quad;  // 8B k-granule 0..7
#pragma unroll
      for (int mt = 0; mt < 4; mt++) {
        int r = mt * 16 + l16;               // P row (combined 0..63)
        a[mt] = *(const long*)(&SA[b][r * 64 + ((cg ^ (r & 6)) * 8)]);
      }
#pragma unroll
      for (int nt = 0; nt < 2; nt++) {
        int r = 64 + wc + nt * 16 + l16;     // W row (combined 64..191)
        b2[nt] = *(const long*)(&SA[b][r * 64 + ((cg ^ (r & 6)) * 8)]);
      }
      __builtin_amdgcn_s_setprio(1);
#pragma unroll
      for (int mt = 0; mt < 4; mt++)
#pragma unroll
        for (int nt = 0; nt < 2; nt++)
          acc[mt][nt] = __builtin_amdgcn_mfma_f32_16x16x32_fp8_fp8(a[mt], b2[nt], acc[mt][nt], 0, 0, 0);
      __builtin_amdgcn_s_setprio(0);
    }
  };

  // prologue: 4 slabs in flight (12 loads)
#pragma unroll
  for (int s = 0; s < 4; s++) issue(s * 64, s);

  // 15 paired iterations; one barrier per pair
#pragma unroll 1
  for (int i = 0; i < 15; i++) {
    __builtin_amdgcn_s_waitcnt(WC_VM6);
    asm volatile("" ::: "memory");
    __builtin_amdgcn_s_barrier();   // all waves: pair i landed; pair i-1's
                                    // ds_reads retired everywhere
    asm volatile("" ::: "memory");
    if (i < 14) {
      issue((2 * i + 4) * 64, (2 * i + 4) % 6);
      issue((2 * i + 5) * 64, (2 * i + 5) % 6);
    }
    consume((2 * i) % 6);
    consume((2 * i + 1) % 6);
  }

  // peeled final pair (i = 15): full drain, constant waitcnt
  __builtin_amdgcn_s_waitcnt(WC_VM0);
  asm volatile("" ::: "memory");
  __builtin_amdgcn_s_barrier();
  asm volatile("" ::: "memory");
  consume(30 % 6);
  consume(31 % 6);

  // C/D layout: col = lane&15, row = quad*4 + reg (verified). Undo 256x scale.
#pragma unroll
  for (int mt = 0; mt < 4; mt++)
#pragma unroll
    for (int nt = 0; nt < 2; nt++)
#pragma unroll
      for (int e = 0; e < 4; e++) {
        int row = i0 + mt * 16 + quad * 4 + e;
        int col = j0 + wc + nt * 16 + l16;
        out[(size_t)row * NN + col] = acc[mt][nt][e] * 0.00390625f;
      }
}

extern "C" void kernel_launch(void* const* d_in, const int* in_sizes, int n_in,
                              void* d_out, int out_size, void* d_ws, size_t ws_size,
                              hipStream_t stream) {
  const float* M = (const float*)d_in[0];
  float* out = (float*)d_out;
  char* ws = (char*)d_ws;

  u64* recU = (u64*)(ws + 4096);          // 512 x 8 B (u quads, even tags)
  u64* recV = (u64*)(ws + 20480);         // 512 x 8 B (v quads, odd tags)
  unsigned char* Pb = (unsigned char*)(ws + (1u << 20));
  unsigned char* Wb = (unsigned char*)(ws + (1u << 20) + (8u << 20));

  // R15-R17: no memset. ws is re-poisoned to 0xAA every call; poison low2
  // bits = 2 never match the first-generation tags (u: 3/1, v: 0), and the
  // only tag2=2 polls (v gen 5+) occur after every recV word was written.

  sinkhorn_kernel<<<dim3(NBLK), dim3(256), 0, stream>>>(M, recU, recV, Pb, Wb);
  gemm_nt_fp8<<<dim3(512), dim3(256), 0, stream>>>(Pb, Wb, out);
}

// Round 6
// 121.499 us; speedup vs baseline: 2.5306x; 2.5306x over previous
//
#include <hip/hip_runtime.h>
#include <hip/hip_fp16.h>

#define NN 2048
#define ITERS 1000
#define NBLK 256
#define RPW 8  // rows (and cols) per workgroup
#define EPS 3e-3f

typedef __attribute__((ext_vector_type(4))) float floatx4;
typedef unsigned long long u64;

#define AGENT __HIP_MEMORY_SCOPE_AGENT
#define WG __HIP_MEMORY_SCOPE_WORKGROUP

// s_waitcnt simm16 encodings (gfx9): vmcnt[3:0]@[3:0], vmcnt[5:4]@[15:14],
// expcnt@[6:4], lgkmcnt@[11:8]
#define WC_VM6   0x0F76  // vmcnt(6)  lgkm(15) exp(7)
#define WC_VM0   0x0F70  // vmcnt(0)  lgkm(15) exp(7)

static __device__ __forceinline__ void agstore64(u64* p, u64 v) {
  __hip_atomic_store(p, v, __ATOMIC_RELAXED, AGENT);
}
static __device__ __forceinline__ u64 agload64(const u64* p) {
  return __hip_atomic_load(p, __ATOMIC_RELAXED, AGENT);
}

// R19: f16x4 packed exchange, SPLIT-TAG. R18's 2-bits-from-one-mantissa left
// value0 on an 8-bit-mantissa grid (1 ulp = 3.9e-3 rel); quantized Sinkhorn
// settles into +-1-ulp limit cycles, so one toggling value0 held the
// residual above EPS=3e-3 forever -> all 1000 iterations ran (R18 bank-
// conflict arithmetic: 717/iter x ~1000). Fix: steal ONE LSB each from
// value0 and value1 (9-bit mantissa, 1-ulp toggle <= 1.95e-3 < EPS, 35%
// margin; values2,3 full f16, toggle 9.8e-4).
// Tag remap (poison safety): split-extracted poison 0xAA.. gives t2=0, so
// t2=0 must never be polled -> t2 alternates {3,1} for BOTH channels
// (recU/recV are separate arrays; no cross-talk). First polls use 3 != 0.
// Period-2 ABA safety: each polling thread re-reads the SAME address across
// generations; per-location read coherence forbids seeing gen k after it
// observed gen k+1 during the previous gather, and producer skew is <= 1
// generation (transitive gather argument). So a t2 match is always the
// intended generation.
static __device__ __forceinline__ unsigned tagbits(unsigned tag) {
  return ((tag >> 1) & 1u) ? 3u : 1u;
}
static __device__ __forceinline__ unsigned short f16b(float x) {
  return __half_as_ushort(__float2half(x));
}
static __device__ __forceinline__ float f16f(unsigned short b) {
  return __half2float(__ushort_as_half(b));
}
static __device__ __forceinline__ u64 pack4(float a, float b, float c, float d,
                                            unsigned t2) {
  unsigned short ha = (unsigned short)((f16b(a) & 0xFFFEu) | (t2 >> 1));
  unsigned short hb = (unsigned short)((f16b(b) & 0xFFFEu) | (t2 & 1u));
  return ((u64)f16b(d) << 48) | ((u64)f16b(c) << 32) | ((u64)hb << 16) |
         (u64)ha;
}

static __device__ __forceinline__ void poll2(const u64* rec, int tid,
                                             unsigned t2, float* x) {
  const u64* base = rec + tid * 2;
  unsigned got = 0;
  while (got != 0x3u) {
#pragma unroll
    for (int j = 0; j < 2; j++)
      if (!(got & (1u << j))) {
        u64 wv = agload64(base + j);
        unsigned t = (((unsigned)wv & 1u) << 1) | ((unsigned)(wv >> 16) & 1u);
        if (t == t2) {
          x[4 * j + 0] = f16f((unsigned short)(wv & 0xFFFEu));
          x[4 * j + 1] = f16f((unsigned short)((wv >> 16) & 0xFFFEu));
          x[4 * j + 2] = f16f((unsigned short)(wv >> 32));
          x[4 * j + 3] = f16f((unsigned short)(wv >> 48));
          got |= 1u << j;
        }
      }
  }
}

static __device__ __forceinline__ void gather64(const u64* rec, int tid,
                                                float* vec, unsigned tag) {
  float x[8];
  poll2(rec, tid, tagbits(tag), x);
#pragma unroll
  for (int j = 0; j < 8; j++) vec[tid * 8 + j] = x[j];
  __syncthreads();
}

static __device__ __forceinline__ bool gather64_check(const u64* rec, int tid,
                                                      float* vec, unsigned tag,
                                                      float* pv) {
  float x[8];
  poll2(rec, tid, tagbits(tag), x);
  float resid = 0.f;
#pragma unroll
  for (int j = 0; j < 8; j++) {
    resid = fmaxf(resid, fabsf(x[j] / pv[j] - 1.0f));
    pv[j] = x[j];
    vec[tid * 8 + j] = x[j];
  }
  return __syncthreads_and(resid < EPS) != 0;
}

// Pair-group publish: waves (2q, 2q+1) share word 2g+q (rows 8g+4q..+3).
// Odd wave hands its two values to the even wave via LDS (release flag =
// exchange tag, strictly increasing -> no reset needed); even wave packs
// 4xf16 and issues the single MALL store. No added MALL round-trips.
// No deadlock: odd's next gather needs even's store; even's spin needs
// odd's flag, which odd sets unconditionally before gathering.
static __device__ __forceinline__ void publish_pair(u64* rec, int g, int w,
                                                    int lane, float va,
                                                    float vb, float* hand,
                                                    unsigned* handflag,
                                                    unsigned tag) {
  if (lane == 0) {
    int q = w >> 1, r0 = 2 * w;
    if (w & 1) {
      hand[r0] = va;
      hand[r0 + 1] = vb;
      __hip_atomic_store(&handflag[q], tag, __ATOMIC_RELEASE, WG);
    } else {
      while (__hip_atomic_load(&handflag[q], __ATOMIC_ACQUIRE, WG) != tag) {}
      agstore64(&rec[2 * g + q],
                pack4(va, vb, hand[r0 + 2], hand[r0 + 3], tagbits(tag)));
    }
  }
}

__global__ __launch_bounds__(256) void sinkhorn_kernel(
    const float* __restrict__ M, u64* recU, u64* recV,
    unsigned char* __restrict__ Pb, unsigned char* __restrict__ Wb)
{
  __shared__ float rowsA[RPW][NN];   // 64 KB: exp(100*M) rows (wave-local)
  __shared__ float colsA[RPW][NN];   // 64 KB: exp(100*M) cols (transposed)
  __shared__ float vec[NN];          // 8 KB: gathered u or v
  __shared__ float myu[RPW];
  __shared__ float hand[RPW];        // odd->even wave value hand-off
  __shared__ unsigned handflag[2];   // per pair-group generation flag

  const int g = blockIdx.x;
  const int tid = threadIdx.x;
  const int w = tid >> 6;
  const int lane = tid & 63;
  const int r0 = 2 * w, r1 = r0 + 1;

  // Row slab load with FUSED exp (no rowmax shift needed: a left-diagonal
  // factor is absorbed by u at the first row normalization; M in
  // (-0.0221,0.0221) -> exp(100M) in (0.11,9.2), no overflow). R11-verified.
  {
    const float4* src = (const float4*)(M + (size_t)g * RPW * NN);
    float4* dst = (float4*)&rowsA[0][0];
    for (int c = tid; c < RPW * NN / 4; c += 256) {
      float4 x = src[c];
      x.x = __expf(100.0f * x.x);
      x.y = __expf(100.0f * x.y);
      x.z = __expf(100.0f * x.z);
      x.w = __expf(100.0f * x.w);
      dst[c] = x;
    }
  }
  if (tid < 2) handflag[tid] = 0;  // covered by the syncthreads below

  // column strip loads into registers (overlap everything)
  float4 sx0[8], sx1[8];
#pragma unroll
  for (int rr = 0; rr < 8; rr++) {
    const float* src = M + (size_t)(tid * 8 + rr) * NN + RPW * g;
    sx0[rr] = *(const float4*)src;
    sx1[rr] = *(const float4*)(src + 4);
  }

  __syncthreads();  // rowsA ready; rows wave-local after this

  // v=1 row sums (wave-local), publish u tag 2
  float s0 = 0.f, s1 = 0.f;
#pragma unroll 8
  for (int k = lane; k < NN; k += 64) {
    s0 += rowsA[r0][k];
    s1 += rowsA[r1][k];
  }
  for (int off = 32; off; off >>= 1) {
    s0 += __shfl_xor(s0, off, 64);
    s1 += __shfl_xor(s1, off, 64);
  }
  {
    float u0 = 1.0f / s0, u1 = 1.0f / s1;
    if (lane == 0) {
      myu[r0] = u0;
      myu[r1] = u1;
    }
    publish_pair(recU, g, w, lane, u0, u1, hand, handflag, 2);
  }

  // colsA = exp(100*strip), off the critical path
#pragma unroll
  for (int rr = 0; rr < 8; rr++) {
    int i = tid * 8 + rr;
    colsA[0][i] = __expf(100.0f * sx0[rr].x);
    colsA[1][i] = __expf(100.0f * sx0[rr].y);
    colsA[2][i] = __expf(100.0f * sx0[rr].z);
    colsA[3][i] = __expf(100.0f * sx0[rr].w);
    colsA[4][i] = __expf(100.0f * sx1[rr].x);
    colsA[5][i] = __expf(100.0f * sx1[rr].y);
    colsA[6][i] = __expf(100.0f * sx1[rr].z);
    colsA[7][i] = __expf(100.0f * sx1[rr].w);
  }

  // it=0 col pass
  float pv[8];
#pragma unroll
  for (int j = 0; j < 8; j++) pv[j] = 1.0f;

  gather64(recU, tid, vec, 2);  // barrier also covers colsA writes
  {
    float t0 = 0.f, t1 = 0.f;
#pragma unroll 8
    for (int k = lane; k < NN; k += 64) {
      float uu = vec[k];
      t0 += colsA[r0][k] * uu;
      t1 += colsA[r1][k] * uu;
    }
    for (int off = 32; off; off >>= 1) {
      t0 += __shfl_xor(t0, off, 64);
      t1 += __shfl_xor(t1, off, 64);
    }
    publish_pair(recV, g, w, lane, 1.0f / t0, 1.0f / t1, hand, handflag, 3);
  }

  // main loop: u tags 2+2it, v tags 3+2it
  bool done = false;
  unsigned utag = 4;
  for (int it = 1; it < ITERS; it++, utag += 2) {
    if (gather64_check(recV, tid, vec, utag - 1, pv)) { done = true; break; }
    float a0 = 0.f, a1 = 0.f;
#pragma unroll 8
    for (int k = lane; k < NN; k += 64) {
      float vv = vec[k];
      a0 += rowsA[r0][k] * vv;
      a1 += rowsA[r1][k] * vv;
    }
    for (int off = 32; off; off >>= 1) {
      a0 += __shfl_xor(a0, off, 64);
      a1 += __shfl_xor(a1, off, 64);
    }
    {
      float u0 = 1.0f / a0, u1 = 1.0f / a1;
      if (lane == 0) {
        myu[r0] = u0;
        myu[r1] = u1;
      }
      publish_pair(recU, g, w, lane, u0, u1, hand, handflag, utag);
    }

    gather64(recU, tid, vec, utag);
    float t0 = 0.f, t1 = 0.f;
#pragma unroll 8
    for (int k = lane; k < NN; k += 64) {
      float uu = vec[k];
      t0 += colsA[r0][k] * uu;
      t1 += colsA[r1][k] * uu;
    }
    for (int off = 32; off; off >>= 1) {
      t0 += __shfl_xor(t0, off, 64);
      t1 += __shfl_xor(t1, off, 64);
    }
    publish_pair(recV, g, w, lane, 1.0f / t0, 1.0f / t1, hand, handflag,
                 utag + 1);
  }
  if (!done) gather64(recV, tid, vec, 2 * ITERS + 1);

  // epilogue: P = 256*diag(u) m0 diag(v) (e4m3), W = row suffix sums (e4m3)
  for (int idx = tid; idx < RPW * NN / 2; idx += 256) {
    int r = idx >> 10, j2 = (idx & 1023) * 2;
    float p0 = 256.0f * myu[r] * rowsA[r][j2] * vec[j2];
    float p1 = 256.0f * myu[r] * rowsA[r][j2 + 1] * vec[j2 + 1];
    int pk = __builtin_amdgcn_cvt_pk_fp8_f32(p0, p1, 0, false);
    ((unsigned short*)Pb)[((((size_t)(RPW * g + r)) << 11) | j2) >> 1] = (unsigned short)pk;
  }
  for (int rr = 0; rr < 2; rr++) {
    int r = 2 * w + rr;
    float ur = myu[r];
    int base = lane * 32;
    float cs = 0.f;
    for (int t = 0; t < 32; t++) {
      int k = base + ((t + lane) & 31);  // rotated: dodge bank conflicts
      cs += ur * rowsA[r][k] * vec[k];
    }
    float s = cs;
    for (int off = 1; off < 64; off <<= 1) {
      float t = __shfl_down(s, off, 64);
      if (lane + off < 64) s += t;
    }
    float run = __shfl_down(s, 1, 64);  // sum of later chunks
    if (lane == 63) run = 0.f;
    float wv[32];
#pragma unroll
    for (int k = 31; k >= 0; k--) {
      int kk = base + k;
      run += ur * rowsA[r][kk] * vec[kk];
      wv[k] = run;
    }
#pragma unroll
    for (int pq = 0; pq < 16; pq++) {
      int pk = __builtin_amdgcn_cvt_pk_fp8_f32(wv[2 * pq], wv[2 * pq + 1], 0, false);
      ((unsigned short*)Wb)[((((size_t)(RPW * g + r)) << 11) | (base + 2 * pq)) >> 1] =
          (unsigned short)pk;
    }
  }
}

// out[i][j] = (1/256) * sum_a P[i][a] * W[j][a]  (NT GEMM, e4m3 in, fp32 out)
//
// R17/R18 (kept): TWO SLABS PER BARRIER, final pair peeled (s_waitcnt arg
// must be literal). Per pair: wait vmcnt(6) [pair landed; 2 slabs x 3 loads
// in flight], barrier, issue next pair, consume pair. Ring-6 safety: iter-i
// issue targets the pair consumed at iter i-1; any wave past barrier i
// already retired those ds_reads (lgkmcnt forced before its MFMAs).
// 64x128 tiles, grid 512 = 2 blocks/CU, 72 KB LDS; XOR-granule swizzle and
// XCD pinning (blk%8 = by%8) bit-identical.
__global__ __launch_bounds__(256, 2) void gemm_nt_fp8(const unsigned char* __restrict__ P,
                                                      const unsigned char* __restrict__ W,
                                                      float* __restrict__ out)
{
  __shared__ unsigned char SA[6][12288];  // 72 KB
  const int tid = threadIdx.x;
  const int w = tid >> 6, lane = tid & 63;
  const int quad = lane >> 4, l16 = lane & 15;
  const int by = blockIdx.x & 15;   // W-strip id -> pins XCD (blk%8 = by%8)
  const int bx = blockIdx.x >> 4;   // P-strip id (0..31)
  const int i0 = bx * 64, j0 = by * 128;
  const int wc = w * 32;            // wave N base within tile

  const int lrow = lane >> 2;        // staging row within 16-row chunk
  const int lp2 = (lane & 3) * 2;    // staging granule pair base

  floatx4 acc[4][2] = {};

  // issue one 64-wide K-slab into buffer b: 12 chunks of 1 KB, 3 per wave.
  // rows 0..63 = P tile rows, rows 64..191 = W tile rows.
  auto issue = [&](int k0, int b) {
#pragma unroll
    for (int c = 0; c < 3; c++) {
      int q = w * 3 + c;           // wave-uniform chunk id 0..11
      int r = q * 16 + lrow;       // combined row 0..191
      const unsigned char* gsrc =
          (q < 4 ? P + (size_t)(i0 + r) * NN
                 : W + (size_t)(j0 + r - 64) * NN) +
          k0 + ((lp2 ^ (r & 6)) * 8);
      __builtin_amdgcn_global_load_lds(
          (const __attribute__((address_space(1))) void*)gsrc,
          (__attribute__((address_space(3))) void*)(&SA[b][q * 1024]), 16, 0, 0);
    }
  };

  // consume one slab from buffer b
  auto consume = [&](int b) {
#pragma unroll
    for (int kc = 0; kc < 2; kc++) {
      long a[4], b2[2];
      int cg = kc * 4 + quad;  // 8B k-granule 0..7
#pragma unroll
      for (int mt = 0; mt < 4; mt++) {
        int r = mt * 16 + l16;               // P row (combined 0..63)
        a[mt] = *(const long*)(&SA[b][r * 64 + ((cg ^ (r & 6)) * 8)]);
      }
#pragma unroll
      for (int nt = 0; nt < 2; nt++) {
        int r = 64 + wc + nt * 16 + l16;     // W row (combined 64..191)
        b2[nt] = *(const long*)(&SA[b][r * 64 + ((cg ^ (r & 6)) * 8)]);
      }
      __builtin_amdgcn_s_setprio(1);
#pragma unroll
      for (int mt = 0; mt < 4; mt++)
#pragma unroll
        for (int nt = 0; nt < 2; nt++)
          acc[mt][nt] = __builtin_amdgcn_mfma_f32_16x16x32_fp8_fp8(a[mt], b2[nt], acc[mt][nt], 0, 0, 0);
      __builtin_amdgcn_s_setprio(0);
    }
  };

  // prologue: 4 slabs in flight (12 loads)
#pragma unroll
  for (int s = 0; s < 4; s++) issue(s * 64, s);

  // 15 paired iterations; one barrier per pair
#pragma unroll 1
  for (int i = 0; i < 15; i++) {
    __builtin_amdgcn_s_waitcnt(WC_VM6);
    asm volatile("" ::: "memory");
    __builtin_amdgcn_s_barrier();   // all waves: pair i landed; pair i-1's
                                    // ds_reads retired everywhere
    asm volatile("" ::: "memory");
    if (i < 14) {
      issue((2 * i + 4) * 64, (2 * i + 4) % 6);
      issue((2 * i + 5) * 64, (2 * i + 5) % 6);
    }
    consume((2 * i) % 6);
    consume((2 * i + 1) % 6);
  }

  // peeled final pair (i = 15): full drain, constant waitcnt
  __builtin_amdgcn_s_waitcnt(WC_VM0);
  asm volatile("" ::: "memory");
  __builtin_amdgcn_s_barrier();
  asm volatile("" ::: "memory");
  consume(30 % 6);
  consume(31 % 6);

  // C/D layout: col = lane&15, row = quad*4 + reg (verified). Undo 256x scale.
#pragma unroll
  for (int mt = 0; mt < 4; mt++)
#pragma unroll
    for (int nt = 0; nt < 2; nt++)
#pragma unroll
      for (int e = 0; e < 4; e++) {
        int row = i0 + mt * 16 + quad * 4 + e;
        int col = j0 + wc + nt * 16 + l16;
        out[(size_t)row * NN + col] = acc[mt][nt][e] * 0.00390625f;
      }
}

extern "C" void kernel_launch(void* const* d_in, const int* in_sizes, int n_in,
                              void* d_out, int out_size, void* d_ws, size_t ws_size,
                              hipStream_t stream) {
  const float* M = (const float*)d_in[0];
  float* out = (float*)d_out;
  char* ws = (char*)d_ws;

  u64* recU = (u64*)(ws + 4096);          // 512 x 8 B (u quads, even tags)
  u64* recV = (u64*)(ws + 20480);         // 512 x 8 B (v quads, odd tags)
  unsigned char* Pb = (unsigned char*)(ws + (1u << 20));
  unsigned char* Wb = (unsigned char*)(ws + (1u << 20) + (8u << 20));

  // R15-R19: no memset. ws is re-poisoned to 0xAA every call; split-tag
  // extraction of poison yields t2=0, and t2=0 is never polled (t2 alternates
  // {3,1} for both channels), so poll2 cannot false-match poison.

  sinkhorn_kernel<<<dim3(NBLK), dim3(256), 0, stream>>>(M, recU, recV, Pb, Wb);
  gemm_nt_fp8<<<dim3(512), dim3(256), 0, stream>>>(Pb, Wb, out);
}